// Round 19
// baseline (342.952 us; speedup 1.0000x reference)
//
#include <hip/hip_runtime.h>
#include <stdint.h>

#define BETA 0.9f
#define NIN 784
#define KA0 832            // 784 padded to multiple of 64
#define NHID 2048
#define BATCH 128
#define TSTEPS 32
#define MROWS 4096         // 32*128
#define NB 1024            // stat partial slots per job

typedef float f32x4 __attribute__((ext_vector_type(4)));
typedef int   i32x4 __attribute__((ext_vector_type(4)));

// i8 plane scales (powers of 2; decomposition residual <= 2^-28; verified r10/r12 absmax 1.9e-6)
#define S1F 0x1p-11f
#define S2F 0x1p-19f
#define S3F 0x1p-27f

// ---------- helpers ----------
__device__ __forceinline__ float nofuse(float x) {  // block fp-contraction
  asm volatile("" : "+v"(x));
  return x;
}

typedef __attribute__((address_space(1))) const unsigned int gas_uint;
typedef __attribute__((address_space(3))) unsigned int las_uint;
__device__ __forceinline__ void gload_lds16(const void* g, void* l) {
  __builtin_amdgcn_global_load_lds((gas_uint*)g, (las_uint*)l, 16, 0, 0);
}

// ---------- ws layout ----------
static const size_t SZ_WS0   = (size_t)3 * 2048 * KA0;        // i8
static const size_t SZ_WSH   = (size_t)3 * 2048 * 2048;       // i8
static const size_t SZ_W4T   = (size_t)2048 * 16 * 4;
static const size_t SZ_SPK   = (size_t)MROWS * 2048;          // i8
static const size_t SZ_CUR   = (size_t)MROWS * 2048 * 4;
static const size_t SZ_VST   = (size_t)5 * TSTEPS * NB * 2 * 4;
static const size_t SZ_CST   = (size_t)6 * TSTEPS * NB * 4;
static const size_t SZ_CUR5P = (size_t)MROWS * 16 * 8 * 4;    // split-K x8 partials

static const size_t OFF_WS0   = 0;
static const size_t OFF_WS1   = OFF_WS0 + SZ_WS0;
static const size_t OFF_WS2   = OFF_WS1 + SZ_WSH;
static const size_t OFF_WS3   = OFF_WS2 + SZ_WSH;
static const size_t OFF_W4T   = OFF_WS3 + SZ_WSH;
static const size_t OFF_SPKA  = OFF_W4T + SZ_W4T;
static const size_t OFF_SPKB  = OFF_SPKA + SZ_SPK;
static const size_t OFF_CUR   = OFF_SPKB + SZ_SPK;
static const size_t OFF_VST   = OFF_CUR + SZ_CUR;
static const size_t OFF_CST   = OFF_VST + SZ_VST;
static const size_t OFF_CUR5P = OFF_CST + SZ_CST;

// ---------- prep: split fp32 W into 3 exact i8 planes (fused all 4 weights) ----------
__device__ __forceinline__ void wsplit_one(const float* __restrict__ W,
                                           signed char* __restrict__ dst,
                                           int idx, int nrows, int kvalid, int kpad) {
  int kq = kvalid >> 2;
  if (idx >= nrows * kq) return;
  int row = idx / kq, k0 = (idx - row * kq) * 4;
  const float* src = W + (size_t)row * kvalid + k0;
  signed char p1[4], p2[4], p3[4];
#pragma unroll
  for (int e = 0; e < 4; ++e) {
    float f = src[e];
    float q1 = rintf(f * 2048.0f);
    float r1 = f - q1 * S1F;                       // exact
    float q2 = rintf(r1 * 524288.0f);              // 2^19
    q2 = fminf(127.f, fmaxf(-127.f, q2));
    float r2 = r1 - q2 * S2F;                      // exact
    float q3 = rintf(r2 * 134217728.0f);           // 2^27
    q3 = fminf(127.f, fmaxf(-127.f, q3));
    p1[e] = (signed char)(int)q1;
    p2[e] = (signed char)(int)q2;
    p3[e] = (signed char)(int)q3;
  }
  size_t base = (size_t)row * kpad + k0;
  size_t plane = (size_t)nrows * kpad;
  *(char4*)(dst + base)             = make_char4(p1[0], p1[1], p1[2], p1[3]);
  *(char4*)(dst + plane + base)     = make_char4(p2[0], p2[1], p2[2], p2[3]);
  *(char4*)(dst + 2 * plane + base) = make_char4(p3[0], p3[1], p3[2], p3[3]);
}

__global__ void k_wsplit_all(const float* __restrict__ W0, const float* __restrict__ W1,
                             const float* __restrict__ W2, const float* __restrict__ W3,
                             signed char* __restrict__ d0, signed char* __restrict__ d1,
                             signed char* __restrict__ d2, signed char* __restrict__ d3) {
  int blk = blockIdx.x;
  if (blk < 1568) {
    wsplit_one(W0, d0, blk * 256 + threadIdx.x, 2048, NIN, KA0);
  } else {
    int j = blk - 1568;
    int w = j >> 12, r = j & 4095;
    int idx = r * 256 + threadIdx.x;
    if (w == 0)      wsplit_one(W1, d1, idx, 2048, 2048, 2048);
    else if (w == 1) wsplit_one(W2, d2, idx, 2048, 2048, 2048);
    else             wsplit_one(W3, d3, idx, 2048, 2048, 2048);
  }
}

__global__ void k_w4t(const float* __restrict__ W4, float* __restrict__ w4t) {
  int k = blockIdx.x * blockDim.x + threadIdx.x;
  if (k >= 2048) return;
#pragma unroll
  for (int c = 0; c < 16; ++c)
    w4t[(size_t)k * 16 + c] = (c < 10) ? W4[(size_t)c * 2048 + k] : 0.f;
}

// =====================================================================
// Main GEMM (r16-proven optimum, unchanged): i8 MFMA 16x16x64, per-plane
// i32 acc through MFMA C (exact), fp32 fold at epilogue. Single sync per
// K-step; stage source pointers precomputed once, advanced +64 B/step.
// BM=BN=128, BK=64, 256 thr, 4 waves, per-wave 64x64. dbuf 64KB.
// =====================================================================
__global__ __launch_bounds__(256, 2) void k_gemm3p(
    const signed char* __restrict__ A,   // [M][Ka] spikes 0/1
    const signed char* __restrict__ B,   // [3][N][Ka] weight planes
    float* __restrict__ C,               // [M][N]
    int N, int Ka) {
  __shared__ __align__(16) signed char smem[2][32768]; // per buf: A[0,8192) | B s*8192
  const int tid = threadIdx.x;
  const int lane = tid & 63, wv = tid >> 6;

  const int bid = blockIdx.x;
  const int xcd = bid & 7, lid = bid >> 3;
  const int by = (xcd >> 1) * 8 + (lid >> 3);        // 0..31
  const int bx = (xcd & 1) * 8 + (lid & 7);          // 0..15
  const int m0 = by * 128, n0 = bx * 128;
  const int NT = Ka >> 6;

  i32x4 acc0[4][4], acc1[4][4], acc2[4][4];
#pragma unroll
  for (int i = 0; i < 4; ++i)
#pragma unroll
    for (int j = 0; j < 4; ++j) {
      acc0[i][j] = (i32x4){0, 0, 0, 0};
      acc1[i][j] = (i32x4){0, 0, 0, 0};
      acc2[i][j] = (i32x4){0, 0, 0, 0};
    }

  const signed char* srcb[8];
#pragma unroll
  for (int i = 0; i < 8; ++i) {
    int c = i * 256 + tid;
    if (c < 512) {                         // A: 128 rows x 64 i8
      int row = c >> 2, kb = c & 3;
      int gkb = kb ^ ((row >> 1) & 3);     // source pre-swizzle (rule #21)
      srcb[i] = A + (size_t)(m0 + row) * Ka + gkb * 16;
    } else {                               // B planes: 3 x (128 rows x 64 i8)
      int cb = c - 512;
      int s = cb >> 9, cc = cb & 511;
      int row = cc >> 2, kb = cc & 3;
      int gkb = kb ^ ((row >> 1) & 3);
      srcb[i] = B + ((size_t)s * N + n0 + row) * Ka + gkb * 16;
    }
  }
  auto stage_all = [&](int buf, int kt) {
    const int koff = kt * 64;
#pragma unroll
    for (int i = 0; i < 8; ++i)
      gload_lds16(srcb[i] + koff, &smem[buf][(i * 256 + wv * 64) * 16]);
  };

  const int wm = wv >> 1, wn = wv & 1;
  const int g = lane >> 4, rr = lane & 15;

  auto readA = [&](int p, i32x4* a) {
#pragma unroll
    for (int mf = 0; mf < 4; ++mf) {
      int row = wm * 64 + mf * 16 + rr;
      int slot = g ^ ((row >> 1) & 3);
      a[mf] = *(const i32x4*)&smem[p][row * 64 + slot * 16];
    }
  };
  auto readB = [&](int p, int s, i32x4* b) {
#pragma unroll
    for (int nf = 0; nf < 4; ++nf) {
      int row = wn * 64 + nf * 16 + rr;
      int slot = g ^ ((row >> 1) & 3);
      b[nf] = *(const i32x4*)&smem[p][8192 + s * 8192 + row * 64 + slot * 16];
    }
  };
  auto cluster = [&](i32x4* a, i32x4* b, i32x4 (*acc)[4]) {
    __builtin_amdgcn_s_setprio(1);
#pragma unroll
    for (int mf = 0; mf < 4; ++mf)
#pragma unroll
      for (int nf = 0; nf < 4; ++nf)
        acc[mf][nf] = __builtin_amdgcn_mfma_i32_16x16x64_i8(a[mf], b[nf], acc[mf][nf], 0, 0, 0);
    __builtin_amdgcn_s_setprio(0);
  };

  stage_all(0, 0);

  for (int kt = 0; kt < NT; ++kt) {
    const int p = kt & 1;
    asm volatile("s_waitcnt vmcnt(0)" ::: "memory");
    __builtin_amdgcn_sched_barrier(0);
    __builtin_amdgcn_s_barrier();
    __builtin_amdgcn_sched_barrier(0);

    if (kt + 1 < NT) stage_all(p ^ 1, kt + 1);

    i32x4 a[4], b[4];
    readA(p, a);
    readB(p, 0, b);
    cluster(a, b, acc0);
    readB(p, 1, b);
    cluster(a, b, acc1);
    readB(p, 2, b);
    cluster(a, b, acc2);
  }

#pragma unroll
  for (int mf = 0; mf < 4; ++mf)
#pragma unroll
    for (int nf = 0; nf < 4; ++nf) {
      int col = n0 + wn * 64 + nf * 16 + rr;
#pragma unroll
      for (int v = 0; v < 4; ++v) {
        int row = m0 + wm * 64 + mf * 16 + g * 4 + v;  // D: row=(lane>>4)*4+reg, col=lane&15
        float f = S1F * (float)acc0[mf][nf][v];
        f = __fmaf_rn(S2F, (float)acc1[mf][nf][v], f);
        f = __fmaf_rn(S3F, (float)acc2[mf][nf][v], f);
        C[(size_t)row * N + col] = f;
      }
    }
}

// ---------- LIF scans ----------
// layer 0: static input, D=784 (pad 832), grid=128, 128 thr; i8 spikes out
__global__ __launch_bounds__(128) void k_scan0(
    const float* __restrict__ input, signed char* __restrict__ spk0,
    float* __restrict__ vstats, int* __restrict__ cstats) {
  const int b = blockIdx.x, tid = threadIdx.x;
  const int j0 = tid * 8;
  const bool act = (j0 < NIN);
  const int lane = tid & 63, wv = tid >> 6;
  __shared__ float ssum[2][TSTEPS], ssq[2][TSTEPS];
  __shared__ int scnt[2][TSTEPS];
  float iv[8];
  if (act) {
    const float* ip = input + (size_t)b * NIN + j0;
    float4 c0 = *(const float4*)ip, c1 = *(const float4*)(ip + 4);
    iv[0]=c0.x; iv[1]=c0.y; iv[2]=c0.z; iv[3]=c0.w;
    iv[4]=c1.x; iv[5]=c1.y; iv[6]=c1.z; iv[7]=c1.w;
  } else {
#pragma unroll
    for (int e = 0; e < 8; ++e) iv[e] = 0.f;
  }
  float mem[8] = {0,0,0,0,0,0,0,0};
  for (int t = 0; t < TSTEPS; ++t) {
    float sum = 0.f, sq = 0.f; int cnt = 0;
    unsigned long long pk = 0;
#pragma unroll
    for (int e = 0; e < 8; ++e) {
      float reset = mem[e] > 1.0f ? 1.0f : 0.0f;
      float t1 = nofuse(BETA * mem[e]);
      float t2 = nofuse(t1 + iv[e]);
      float mn = t2 - reset;
      mem[e] = mn;
      int s = mn > 1.0f;
      pk |= (unsigned long long)(s ? 1u : 0u) << (8 * e);
      sum += mn; sq = __fmaf_rn(mn, mn, sq); cnt += s;
    }
    if (act)
      *(unsigned long long*)(spk0 + (size_t)(t * BATCH + b) * KA0 + j0) = pk;
#pragma unroll
    for (int o = 32; o > 0; o >>= 1) {
      sum += __shfl_down(sum, o, 64);
      sq  += __shfl_down(sq, o, 64);
      cnt += __shfl_down(cnt, o, 64);
    }
    if (lane == 0) { ssum[wv][t] = sum; ssq[wv][t] = sq; scnt[wv][t] = cnt; }
  }
  __syncthreads();
  if (tid < TSTEPS) {
    int t = tid;
    float s = ssum[0][t] + ssum[1][t];
    float q = ssq[0][t] + ssq[1][t];
    int c = scnt[0][t] + scnt[1][t];
    vstats[((size_t)(0 * TSTEPS + t) * NB + b) * 2 + 0] = s;
    vstats[((size_t)(0 * TSTEPS + t) * NB + b) * 2 + 1] = q;
    cstats[(0 * TSTEPS + t) * NB + b] = c;
  }
}

// layers 1..4: cur + bias -> LIF -> spk i8. grid 1024 (b x octant), 128 thr,
// 2 fp32/thread (float2 load) -> 128K threads, 8 waves/CU for latency hiding.
__global__ __launch_bounds__(128) void k_scan(
    const float* __restrict__ cur, const float* __restrict__ bias,
    signed char* __restrict__ spk, float* __restrict__ vstats,
    int* __restrict__ cstats, int layer) {
  const int blk = blockIdx.x;
  const int b = blk >> 3, oc = blk & 7;
  const int tid = threadIdx.x;
  const int j0 = oc * 256 + tid * 2;
  const int lane = tid & 63, wv = tid >> 6;
  __shared__ float ssum[2][TSTEPS], ssq[2][TSTEPS];
  __shared__ int scnt[2][TSTEPS];
  float bs[2];
  {
    float2 c0 = *(const float2*)(bias + j0);
    bs[0] = c0.x; bs[1] = c0.y;
  }
  float mem[2] = {0, 0};
  for (int t = 0; t < TSTEPS; ++t) {
    size_t off = (size_t)(t * BATCH + b) * 2048 + j0;
    float2 c0 = *(const float2*)(cur + off);
    float cv[2] = {c0.x, c0.y};
    float sum = 0.f, sq = 0.f; int cnt = 0;
    unsigned short pk = 0;
#pragma unroll
    for (int e = 0; e < 2; ++e) {
      float cc = nofuse(cv[e] + bs[e]);
      float reset = mem[e] > 1.0f ? 1.0f : 0.0f;
      float t1 = nofuse(BETA * mem[e]);
      float t2 = nofuse(t1 + cc);
      float mn = t2 - reset;
      mem[e] = mn;
      int s = mn > 1.0f;
      pk |= (unsigned short)(s ? 1u : 0u) << (8 * e);
      sum += mn; sq = __fmaf_rn(mn, mn, sq); cnt += s;
    }
    *(unsigned short*)(spk + off) = pk;
#pragma unroll
    for (int o = 32; o > 0; o >>= 1) {
      sum += __shfl_down(sum, o, 64);
      sq  += __shfl_down(sq, o, 64);
      cnt += __shfl_down(cnt, o, 64);
    }
    if (lane == 0) { ssum[wv][t] = sum; ssq[wv][t] = sq; scnt[wv][t] = cnt; }
  }
  __syncthreads();
  if (tid < TSTEPS) {
    int t = tid;
    float s = ssum[0][t] + ssum[1][t];
    float q2 = ssq[0][t] + ssq[1][t];
    int c = scnt[0][t] + scnt[1][t];
    vstats[((size_t)(layer * TSTEPS + t) * NB + blk) * 2 + 0] = s;
    vstats[((size_t)(layer * TSTEPS + t) * NB + blk) * 2 + 1] = q2;
    cstats[(layer * TSTEPS + t) * NB + blk] = c;
  }
}

// small final GEMM, split-K x8: cur5p[r][c][kp] = dot over 256-K chunk
__global__ __launch_bounds__(256) void k_gemm4(
    const signed char* __restrict__ spk, const float* __restrict__ w4t,
    float* __restrict__ cur5p) {
  int idx = blockIdx.x * 256 + threadIdx.x;   // 524288 threads
  int c = idx & 15, kp = (idx >> 4) & 7, r = idx >> 7;
  const signed char* sp = spk + (size_t)r * 2048 + kp * 256;
  const float* wp = w4t + (size_t)kp * 256 * 16 + c;
  float acc = 0.f;
  for (int k = 0; k < 256; k += 4) {
    char4 s4 = *(const char4*)(sp + k);
    acc = __fmaf_rn((float)s4.x, wp[(k + 0) * 16], acc);
    acc = __fmaf_rn((float)s4.y, wp[(k + 1) * 16], acc);
    acc = __fmaf_rn((float)s4.z, wp[(k + 2) * 16], acc);
    acc = __fmaf_rn((float)s4.w, wp[(k + 3) * 16], acc);
  }
  cur5p[((size_t)r * 16 + c) * 8 + kp] = acc;
}

// layer 5: LIF over cur5 partials (fixed-order fold), writes spike_out
__global__ __launch_bounds__(640) void k_scan5(
    const float* __restrict__ cur5p, const float* __restrict__ b4,
    float* __restrict__ spike_out, int* __restrict__ cstats) {
  const int tid = threadIdx.x;
  const int idx = blockIdx.x * 640 + tid;
  const int b = idx / 10, j = idx - b * 10;
  const int lane = tid & 63, wv = tid >> 6;
  __shared__ int scnt[10][TSTEPS];
  const float bias = b4[j];
  float mem = 0.f;
  for (int t = 0; t < TSTEPS; ++t) {
    const float* pp = cur5p + ((size_t)(t * BATCH + b) * 16 + j) * 8;
    float cc = 0.f;
#pragma unroll
    for (int p = 0; p < 8; ++p) cc = __fadd_rn(cc, pp[p]);
    cc = nofuse(cc + bias);
    float reset = mem > 1.0f ? 1.0f : 0.0f;
    float t1 = nofuse(BETA * mem);
    float t2 = nofuse(t1 + cc);
    float mn = t2 - reset;
    mem = mn;
    int s = mn > 1.0f;
    spike_out[(size_t)t * 1280 + b * 10 + j] = s ? 1.0f : 0.0f;
    int cnt = s;
#pragma unroll
    for (int o = 32; o > 0; o >>= 1) cnt += __shfl_down(cnt, o, 64);
    if (lane == 0) scnt[wv][t] = cnt;
  }
  __syncthreads();
  if (tid < TSTEPS) {
    int t = tid, c = 0;
#pragma unroll
    for (int w = 0; w < 10; ++w) c += scnt[w][t];
    cstats[(5 * TSTEPS + t) * NB + blockIdx.x] = c;
  }
}

// final reduction — 11 blocks (5 var + 6 count), 32 lane-groups own one t
__global__ __launch_bounds__(1024) void k_final(
    const float* __restrict__ vstats, const int* __restrict__ cstats,
    float* __restrict__ d_out) {
  __shared__ float red[TSTEPS];
  const int blk = blockIdx.x;
  const int tid = threadIdx.x;
  const int t = tid >> 5, ln = tid & 31;
  if (blk < 5) {
    const int l = blk;
    const int j = l * TSTEPS + t;
    double s = 0.0, q = 0.0;
    for (int b = ln; b < NB; b += 32) {
      s += (double)vstats[((size_t)j * NB + b) * 2 + 0];
      q += (double)vstats[((size_t)j * NB + b) * 2 + 1];
    }
#pragma unroll
    for (int o = 1; o < 32; o <<= 1) {
      s += __shfl_xor(s, o, 64);
      q += __shfl_xor(q, o, 64);
    }
    if (ln == 0) {
      double n = (l == 0) ? (double)(BATCH * NIN) : (double)(BATCH * NHID);
      red[t] = (float)((q - s * s / n) / (n - 1.0));
    }
    __syncthreads();
    if (tid == 0) {
      float a = 0.f;
      for (int tt = 0; tt < TSTEPS; ++tt) a = __fadd_rn(a, red[tt]);
      d_out[l] = a / 32.0f;
    }
  } else {
    const int i = blk - 5;
    const int j = i * TSTEPS + t;
    int c = 0;
    for (int b = ln; b < NB; b += 32) c += cstats[j * NB + b];
#pragma unroll
    for (int o = 1; o < 32; o <<= 1) c += __shfl_xor(c, o, 64);
    if (ln == 0) red[t] = (float)c * (1.0f / 128.0f);
    __syncthreads();
    if (tid == 0) {
      float a = 0.f;
      for (int tt = 0; tt < TSTEPS; ++tt) a = __fadd_rn(a, red[tt]);
      d_out[40965 + i] = a / 4096.0f;
    }
  }
}

// ---------- launch ----------
extern "C" void kernel_launch(void* const* d_in, const int* in_sizes, int n_in,
                              void* d_out, int out_size, void* d_ws, size_t ws_size,
                              hipStream_t stream) {
  const float* input = (const float*)d_in[0];
  const float* W0 = (const float*)d_in[1];
  const float* W1 = (const float*)d_in[2];
  const float* W2 = (const float*)d_in[3];
  const float* W3 = (const float*)d_in[4];
  const float* W4 = (const float*)d_in[5];
  const float* b0 = (const float*)d_in[6];
  const float* b1 = (const float*)d_in[7];
  const float* b2 = (const float*)d_in[8];
  const float* b3 = (const float*)d_in[9];
  const float* b4 = (const float*)d_in[10];

  uint8_t* ws = (uint8_t*)d_ws;
  signed char* ws0  = (signed char*)(ws + OFF_WS0);
  signed char* ws1  = (signed char*)(ws + OFF_WS1);
  signed char* ws2  = (signed char*)(ws + OFF_WS2);
  signed char* ws3  = (signed char*)(ws + OFF_WS3);
  float* w4t        = (float*)(ws + OFF_W4T);
  signed char* spkA = (signed char*)(ws + OFF_SPKA);
  signed char* spkB = (signed char*)(ws + OFF_SPKB);
  float* cur        = (float*)(ws + OFF_CUR);
  float* cur5p      = (float*)(ws + OFF_CUR5P);
  float* vst        = (float*)(ws + OFF_VST);
  int* cst          = (int*)(ws + OFF_CST);
  float* out        = (float*)d_out;

  hipMemsetAsync(ws + OFF_VST, 0, SZ_VST + SZ_CST + SZ_CUR5P, stream);
  hipMemsetAsync(ws + OFF_SPKA, 0, (size_t)TSTEPS * BATCH * KA0, stream);
  hipMemsetAsync(ws + OFF_WS0, 0, SZ_WS0, stream);

  k_wsplit_all<<<1568 + 3 * 4096, 256, 0, stream>>>(W0, W1, W2, W3, ws0, ws1, ws2, ws3);
  k_w4t<<<8, 256, 0, stream>>>(W4, w4t);

  k_scan0<<<BATCH, 128, 0, stream>>>(input, spkA, vst, cst);
  k_gemm3p<<<512, 256, 0, stream>>>(spkA, ws0, cur, 2048, KA0);
  k_scan<<<1024, 128, 0, stream>>>(cur, b0, spkB, vst, cst, 1);
  k_gemm3p<<<512, 256, 0, stream>>>(spkB, ws1, cur, 2048, 2048);
  k_scan<<<1024, 128, 0, stream>>>(cur, b1, spkA, vst, cst, 2);
  k_gemm3p<<<512, 256, 0, stream>>>(spkA, ws2, cur, 2048, 2048);
  k_scan<<<1024, 128, 0, stream>>>(cur, b2, spkB, vst, cst, 3);
  k_gemm3p<<<512, 256, 0, stream>>>(spkB, ws3, cur, 2048, 2048);
  k_scan<<<1024, 128, 0, stream>>>(cur, b3, spkA, vst, cst, 4);
  k_gemm4<<<2048, 256, 0, stream>>>(spkA, w4t, cur5p);
  k_scan5<<<2, 640, 0, stream>>>(cur5p, b4, out + 5, cst);
  k_final<<<11, 1024, 0, stream>>>(vst, cst, out);
}

// Round 20
// 336.053 us; speedup vs baseline: 1.0205x; 1.0205x over previous
//
#include <hip/hip_runtime.h>
#include <stdint.h>

#define BETA 0.9f
#define NIN 784
#define KA0 832            // 784 padded to multiple of 64
#define NHID 2048
#define BATCH 128
#define TSTEPS 32
#define MROWS 4096         // 32*128
#define NB 512             // stat partial slots per job

typedef float f32x4 __attribute__((ext_vector_type(4)));
typedef int   i32x4 __attribute__((ext_vector_type(4)));

// i8 plane scales (powers of 2; decomposition residual <= 2^-28; verified r10/r12 absmax 1.9e-6)
#define S1F 0x1p-11f
#define S2F 0x1p-19f
#define S3F 0x1p-27f

// ---------- helpers ----------
__device__ __forceinline__ float nofuse(float x) {  // block fp-contraction
  asm volatile("" : "+v"(x));
  return x;
}

typedef __attribute__((address_space(1))) const unsigned int gas_uint;
typedef __attribute__((address_space(3))) unsigned int las_uint;
__device__ __forceinline__ void gload_lds16(const void* g, void* l) {
  __builtin_amdgcn_global_load_lds((gas_uint*)g, (las_uint*)l, 16, 0, 0);
}

// ---------- ws layout ----------
static const size_t SZ_WS0   = (size_t)3 * 2048 * KA0;        // i8
static const size_t SZ_WSH   = (size_t)3 * 2048 * 2048;       // i8
static const size_t SZ_W4T   = (size_t)2048 * 16 * 4;
static const size_t SZ_SPK   = (size_t)MROWS * 2048;          // i8
static const size_t SZ_CUR   = (size_t)MROWS * 2048 * 4;
static const size_t SZ_VST   = (size_t)5 * TSTEPS * NB * 2 * 4;
static const size_t SZ_CST   = (size_t)6 * TSTEPS * NB * 4;
static const size_t SZ_CUR5P = (size_t)MROWS * 16 * 8 * 4;    // split-K x8 partials

static const size_t OFF_WS0   = 0;
static const size_t OFF_WS1   = OFF_WS0 + SZ_WS0;
static const size_t OFF_WS2   = OFF_WS1 + SZ_WSH;
static const size_t OFF_WS3   = OFF_WS2 + SZ_WSH;
static const size_t OFF_W4T   = OFF_WS3 + SZ_WSH;
static const size_t OFF_SPKA  = OFF_W4T + SZ_W4T;
static const size_t OFF_SPKB  = OFF_SPKA + SZ_SPK;
static const size_t OFF_CUR   = OFF_SPKB + SZ_SPK;
static const size_t OFF_VST   = OFF_CUR + SZ_CUR;
static const size_t OFF_CST   = OFF_VST + SZ_VST;
static const size_t OFF_CUR5P = OFF_CST + SZ_CST;

// ---------- prep: split fp32 W into 3 exact i8 planes (fused all 4 weights) ----------
__device__ __forceinline__ void wsplit_one(const float* __restrict__ W,
                                           signed char* __restrict__ dst,
                                           int idx, int nrows, int kvalid, int kpad) {
  int kq = kvalid >> 2;
  if (idx >= nrows * kq) return;
  int row = idx / kq, k0 = (idx - row * kq) * 4;
  const float* src = W + (size_t)row * kvalid + k0;
  signed char p1[4], p2[4], p3[4];
#pragma unroll
  for (int e = 0; e < 4; ++e) {
    float f = src[e];
    float q1 = rintf(f * 2048.0f);
    float r1 = f - q1 * S1F;                       // exact
    float q2 = rintf(r1 * 524288.0f);              // 2^19
    q2 = fminf(127.f, fmaxf(-127.f, q2));
    float r2 = r1 - q2 * S2F;                      // exact
    float q3 = rintf(r2 * 134217728.0f);           // 2^27
    q3 = fminf(127.f, fmaxf(-127.f, q3));
    p1[e] = (signed char)(int)q1;
    p2[e] = (signed char)(int)q2;
    p3[e] = (signed char)(int)q3;
  }
  size_t base = (size_t)row * kpad + k0;
  size_t plane = (size_t)nrows * kpad;
  *(char4*)(dst + base)             = make_char4(p1[0], p1[1], p1[2], p1[3]);
  *(char4*)(dst + plane + base)     = make_char4(p2[0], p2[1], p2[2], p2[3]);
  *(char4*)(dst + 2 * plane + base) = make_char4(p3[0], p3[1], p3[2], p3[3]);
}

__global__ void k_wsplit_all(const float* __restrict__ W0, const float* __restrict__ W1,
                             const float* __restrict__ W2, const float* __restrict__ W3,
                             signed char* __restrict__ d0, signed char* __restrict__ d1,
                             signed char* __restrict__ d2, signed char* __restrict__ d3) {
  int blk = blockIdx.x;
  if (blk < 1568) {
    wsplit_one(W0, d0, blk * 256 + threadIdx.x, 2048, NIN, KA0);
  } else {
    int j = blk - 1568;
    int w = j >> 12, r = j & 4095;
    int idx = r * 256 + threadIdx.x;
    if (w == 0)      wsplit_one(W1, d1, idx, 2048, 2048, 2048);
    else if (w == 1) wsplit_one(W2, d2, idx, 2048, 2048, 2048);
    else             wsplit_one(W3, d3, idx, 2048, 2048, 2048);
  }
}

__global__ void k_w4t(const float* __restrict__ W4, float* __restrict__ w4t) {
  int k = blockIdx.x * blockDim.x + threadIdx.x;
  if (k >= 2048) return;
#pragma unroll
  for (int c = 0; c < 16; ++c)
    w4t[(size_t)k * 16 + c] = (c < 10) ? W4[(size_t)c * 2048 + k] : 0.f;
}

// =====================================================================
// Main GEMM (r16/r18-proven optimum): i8 MFMA 16x16x64, per-plane i32 acc
// through MFMA C (exact), fp32 fold at epilogue. Single sync per K-step;
// stage source pointers precomputed once, advanced +64 B/step.
// BM=BN=128, BK=64, 256 thr, 4 waves, per-wave 64x64. dbuf 64KB.
// grid 512 = 32mt x 16nt, XCD quadrant map. VGPR-capped ~8 waves/CU.
// =====================================================================
__global__ __launch_bounds__(256, 2) void k_gemm3p(
    const signed char* __restrict__ A,   // [M][Ka] spikes 0/1
    const signed char* __restrict__ B,   // [3][N][Ka] weight planes
    float* __restrict__ C,               // [M][N]
    int N, int Ka) {
  __shared__ __align__(16) signed char smem[2][32768]; // per buf: A[0,8192) | B s*8192
  const int tid = threadIdx.x;
  const int lane = tid & 63, wv = tid >> 6;

  const int bid = blockIdx.x;
  const int xcd = bid & 7, lid = bid >> 3;
  const int by = (xcd >> 1) * 8 + (lid >> 3);        // 0..31
  const int bx = (xcd & 1) * 8 + (lid & 7);          // 0..15
  const int m0 = by * 128, n0 = bx * 128;
  const int NT = Ka >> 6;

  i32x4 acc0[4][4], acc1[4][4], acc2[4][4];
#pragma unroll
  for (int i = 0; i < 4; ++i)
#pragma unroll
    for (int j = 0; j < 4; ++j) {
      acc0[i][j] = (i32x4){0, 0, 0, 0};
      acc1[i][j] = (i32x4){0, 0, 0, 0};
      acc2[i][j] = (i32x4){0, 0, 0, 0};
    }

  const signed char* srcb[8];
#pragma unroll
  for (int i = 0; i < 8; ++i) {
    int c = i * 256 + tid;
    if (c < 512) {                         // A: 128 rows x 64 i8
      int row = c >> 2, kb = c & 3;
      int gkb = kb ^ ((row >> 1) & 3);     // source pre-swizzle (rule #21)
      srcb[i] = A + (size_t)(m0 + row) * Ka + gkb * 16;
    } else {                               // B planes: 3 x (128 rows x 64 i8)
      int cb = c - 512;
      int s = cb >> 9, cc = cb & 511;
      int row = cc >> 2, kb = cc & 3;
      int gkb = kb ^ ((row >> 1) & 3);
      srcb[i] = B + ((size_t)s * N + n0 + row) * Ka + gkb * 16;
    }
  }
  auto stage_all = [&](int buf, int kt) {
    const int koff = kt * 64;
#pragma unroll
    for (int i = 0; i < 8; ++i)
      gload_lds16(srcb[i] + koff, &smem[buf][(i * 256 + wv * 64) * 16]);
  };

  const int wm = wv >> 1, wn = wv & 1;
  const int g = lane >> 4, rr = lane & 15;

  auto readA = [&](int p, i32x4* a) {
#pragma unroll
    for (int mf = 0; mf < 4; ++mf) {
      int row = wm * 64 + mf * 16 + rr;
      int slot = g ^ ((row >> 1) & 3);
      a[mf] = *(const i32x4*)&smem[p][row * 64 + slot * 16];
    }
  };
  auto readB = [&](int p, int s, i32x4* b) {
#pragma unroll
    for (int nf = 0; nf < 4; ++nf) {
      int row = wn * 64 + nf * 16 + rr;
      int slot = g ^ ((row >> 1) & 3);
      b[nf] = *(const i32x4*)&smem[p][8192 + s * 8192 + row * 64 + slot * 16];
    }
  };
  auto cluster = [&](i32x4* a, i32x4* b, i32x4 (*acc)[4]) {
    __builtin_amdgcn_s_setprio(1);
#pragma unroll
    for (int mf = 0; mf < 4; ++mf)
#pragma unroll
      for (int nf = 0; nf < 4; ++nf)
        acc[mf][nf] = __builtin_amdgcn_mfma_i32_16x16x64_i8(a[mf], b[nf], acc[mf][nf], 0, 0, 0);
    __builtin_amdgcn_s_setprio(0);
  };

  stage_all(0, 0);

  for (int kt = 0; kt < NT; ++kt) {
    const int p = kt & 1;
    asm volatile("s_waitcnt vmcnt(0)" ::: "memory");
    __builtin_amdgcn_sched_barrier(0);
    __builtin_amdgcn_s_barrier();
    __builtin_amdgcn_sched_barrier(0);

    if (kt + 1 < NT) stage_all(p ^ 1, kt + 1);

    i32x4 a[4], b[4];
    readA(p, a);
    readB(p, 0, b);
    cluster(a, b, acc0);
    readB(p, 1, b);
    cluster(a, b, acc1);
    readB(p, 2, b);
    cluster(a, b, acc2);
  }

#pragma unroll
  for (int mf = 0; mf < 4; ++mf)
#pragma unroll
    for (int nf = 0; nf < 4; ++nf) {
      int col = n0 + wn * 64 + nf * 16 + rr;
#pragma unroll
      for (int v = 0; v < 4; ++v) {
        int row = m0 + wm * 64 + mf * 16 + g * 4 + v;  // D: row=(lane>>4)*4+reg, col=lane&15
        float f = S1F * (float)acc0[mf][nf][v];
        f = __fmaf_rn(S2F, (float)acc1[mf][nf][v], f);
        f = __fmaf_rn(S3F, (float)acc2[mf][nf][v], f);
        C[(size_t)row * N + col] = f;
      }
    }
}

// ---------- LIF scans ----------
// layer 0: static input, D=784 (pad 832), grid=128, 128 thr; i8 spikes out
__global__ __launch_bounds__(128) void k_scan0(
    const float* __restrict__ input, signed char* __restrict__ spk0,
    float* __restrict__ vstats, int* __restrict__ cstats) {
  const int b = blockIdx.x, tid = threadIdx.x;
  const int j0 = tid * 8;
  const bool act = (j0 < NIN);
  const int lane = tid & 63, wv = tid >> 6;
  __shared__ float ssum[2][TSTEPS], ssq[2][TSTEPS];
  __shared__ int scnt[2][TSTEPS];
  float iv[8];
  if (act) {
    const float* ip = input + (size_t)b * NIN + j0;
    float4 c0 = *(const float4*)ip, c1 = *(const float4*)(ip + 4);
    iv[0]=c0.x; iv[1]=c0.y; iv[2]=c0.z; iv[3]=c0.w;
    iv[4]=c1.x; iv[5]=c1.y; iv[6]=c1.z; iv[7]=c1.w;
  } else {
#pragma unroll
    for (int e = 0; e < 8; ++e) iv[e] = 0.f;
  }
  float mem[8] = {0,0,0,0,0,0,0,0};
  for (int t = 0; t < TSTEPS; ++t) {
    float sum = 0.f, sq = 0.f; int cnt = 0;
    unsigned long long pk = 0;
#pragma unroll
    for (int e = 0; e < 8; ++e) {
      float reset = mem[e] > 1.0f ? 1.0f : 0.0f;
      float t1 = nofuse(BETA * mem[e]);
      float t2 = nofuse(t1 + iv[e]);
      float mn = t2 - reset;
      mem[e] = mn;
      int s = mn > 1.0f;
      pk |= (unsigned long long)(s ? 1u : 0u) << (8 * e);
      sum += mn; sq = __fmaf_rn(mn, mn, sq); cnt += s;
    }
    if (act)
      *(unsigned long long*)(spk0 + (size_t)(t * BATCH + b) * KA0 + j0) = pk;
#pragma unroll
    for (int o = 32; o > 0; o >>= 1) {
      sum += __shfl_down(sum, o, 64);
      sq  += __shfl_down(sq, o, 64);
      cnt += __shfl_down(cnt, o, 64);
    }
    if (lane == 0) { ssum[wv][t] = sum; ssq[wv][t] = sq; scnt[wv][t] = cnt; }
  }
  __syncthreads();
  if (tid < TSTEPS) {
    int t = tid;
    float s = ssum[0][t] + ssum[1][t];
    float q = ssq[0][t] + ssq[1][t];
    int c = scnt[0][t] + scnt[1][t];
    vstats[((size_t)(0 * TSTEPS + t) * NB + b) * 2 + 0] = s;
    vstats[((size_t)(0 * TSTEPS + t) * NB + b) * 2 + 1] = q;
    cstats[(0 * TSTEPS + t) * NB + b] = c;
  }
}

// layers 1..4: cur + bias -> LIF -> spk i8. grid 512 (b x quarter), 128 thr
__global__ __launch_bounds__(128) void k_scan(
    const float* __restrict__ cur, const float* __restrict__ bias,
    signed char* __restrict__ spk, float* __restrict__ vstats,
    int* __restrict__ cstats, int layer) {
  const int blk = blockIdx.x;
  const int b = blk >> 2, q = blk & 3;
  const int tid = threadIdx.x;
  const int j0 = q * 512 + tid * 4;
  const int lane = tid & 63, wv = tid >> 6;
  __shared__ float ssum[2][TSTEPS], ssq[2][TSTEPS];
  __shared__ int scnt[2][TSTEPS];
  float bs[4];
  {
    float4 c0 = *(const float4*)(bias + j0);
    bs[0]=c0.x; bs[1]=c0.y; bs[2]=c0.z; bs[3]=c0.w;
  }
  float mem[4] = {0,0,0,0};
  for (int t = 0; t < TSTEPS; ++t) {
    size_t off = (size_t)(t * BATCH + b) * 2048 + j0;
    float4 c0 = *(const float4*)(cur + off);
    float cv[4] = {c0.x, c0.y, c0.z, c0.w};
    float sum = 0.f, sq = 0.f; int cnt = 0;
    unsigned int pk = 0;
#pragma unroll
    for (int e = 0; e < 4; ++e) {
      float cc = nofuse(cv[e] + bs[e]);
      float reset = mem[e] > 1.0f ? 1.0f : 0.0f;
      float t1 = nofuse(BETA * mem[e]);
      float t2 = nofuse(t1 + cc);
      float mn = t2 - reset;
      mem[e] = mn;
      int s = mn > 1.0f;
      pk |= (unsigned int)(s ? 1u : 0u) << (8 * e);
      sum += mn; sq = __fmaf_rn(mn, mn, sq); cnt += s;
    }
    *(unsigned int*)(spk + off) = pk;
#pragma unroll
    for (int o = 32; o > 0; o >>= 1) {
      sum += __shfl_down(sum, o, 64);
      sq  += __shfl_down(sq, o, 64);
      cnt += __shfl_down(cnt, o, 64);
    }
    if (lane == 0) { ssum[wv][t] = sum; ssq[wv][t] = sq; scnt[wv][t] = cnt; }
  }
  __syncthreads();
  if (tid < TSTEPS) {
    int t = tid;
    float s = ssum[0][t] + ssum[1][t];
    float q2 = ssq[0][t] + ssq[1][t];
    int c = scnt[0][t] + scnt[1][t];
    vstats[((size_t)(layer * TSTEPS + t) * NB + blk) * 2 + 0] = s;
    vstats[((size_t)(layer * TSTEPS + t) * NB + blk) * 2 + 1] = q2;
    cstats[(layer * TSTEPS + t) * NB + blk] = c;
  }
}

// small final GEMM, split-K x8: cur5p[r][c][kp] = dot over 256-K chunk
__global__ __launch_bounds__(256) void k_gemm4(
    const signed char* __restrict__ spk, const float* __restrict__ w4t,
    float* __restrict__ cur5p) {
  int idx = blockIdx.x * 256 + threadIdx.x;   // 524288 threads
  int c = idx & 15, kp = (idx >> 4) & 7, r = idx >> 7;
  const signed char* sp = spk + (size_t)r * 2048 + kp * 256;
  const float* wp = w4t + (size_t)kp * 256 * 16 + c;
  float acc = 0.f;
  for (int k = 0; k < 256; k += 4) {
    char4 s4 = *(const char4*)(sp + k);
    acc = __fmaf_rn((float)s4.x, wp[(k + 0) * 16], acc);
    acc = __fmaf_rn((float)s4.y, wp[(k + 1) * 16], acc);
    acc = __fmaf_rn((float)s4.z, wp[(k + 2) * 16], acc);
    acc = __fmaf_rn((float)s4.w, wp[(k + 3) * 16], acc);
  }
  cur5p[((size_t)r * 16 + c) * 8 + kp] = acc;
}

// layer 5: LIF over cur5 partials (fixed-order fold), writes spike_out
__global__ __launch_bounds__(640) void k_scan5(
    const float* __restrict__ cur5p, const float* __restrict__ b4,
    float* __restrict__ spike_out, int* __restrict__ cstats) {
  const int tid = threadIdx.x;
  const int idx = blockIdx.x * 640 + tid;
  const int b = idx / 10, j = idx - b * 10;
  const int lane = tid & 63, wv = tid >> 6;
  __shared__ int scnt[10][TSTEPS];
  const float bias = b4[j];
  float mem = 0.f;
  for (int t = 0; t < TSTEPS; ++t) {
    const float* pp = cur5p + ((size_t)(t * BATCH + b) * 16 + j) * 8;
    float cc = 0.f;
#pragma unroll
    for (int p = 0; p < 8; ++p) cc = __fadd_rn(cc, pp[p]);
    cc = nofuse(cc + bias);
    float reset = mem > 1.0f ? 1.0f : 0.0f;
    float t1 = nofuse(BETA * mem);
    float t2 = nofuse(t1 + cc);
    float mn = t2 - reset;
    mem = mn;
    int s = mn > 1.0f;
    spike_out[(size_t)t * 1280 + b * 10 + j] = s ? 1.0f : 0.0f;
    int cnt = s;
#pragma unroll
    for (int o = 32; o > 0; o >>= 1) cnt += __shfl_down(cnt, o, 64);
    if (lane == 0) scnt[wv][t] = cnt;
  }
  __syncthreads();
  if (tid < TSTEPS) {
    int t = tid, c = 0;
#pragma unroll
    for (int w = 0; w < 10; ++w) c += scnt[w][t];
    cstats[(5 * TSTEPS + t) * NB + blockIdx.x] = c;
  }
}

// final reduction — 11 blocks (5 var + 6 count), 32 lane-groups own one t
__global__ __launch_bounds__(1024) void k_final(
    const float* __restrict__ vstats, const int* __restrict__ cstats,
    float* __restrict__ d_out) {
  __shared__ float red[TSTEPS];
  const int blk = blockIdx.x;
  const int tid = threadIdx.x;
  const int t = tid >> 5, ln = tid & 31;
  if (blk < 5) {
    const int l = blk;
    const int j = l * TSTEPS + t;
    double s = 0.0, q = 0.0;
    for (int b = ln; b < NB; b += 32) {
      s += (double)vstats[((size_t)j * NB + b) * 2 + 0];
      q += (double)vstats[((size_t)j * NB + b) * 2 + 1];
    }
#pragma unroll
    for (int o = 1; o < 32; o <<= 1) {
      s += __shfl_xor(s, o, 64);
      q += __shfl_xor(q, o, 64);
    }
    if (ln == 0) {
      double n = (l == 0) ? (double)(BATCH * NIN) : (double)(BATCH * NHID);
      red[t] = (float)((q - s * s / n) / (n - 1.0));
    }
    __syncthreads();
    if (tid == 0) {
      float a = 0.f;
      for (int tt = 0; tt < TSTEPS; ++tt) a = __fadd_rn(a, red[tt]);
      d_out[l] = a / 32.0f;
    }
  } else {
    const int i = blk - 5;
    const int j = i * TSTEPS + t;
    int c = 0;
    for (int b = ln; b < NB; b += 32) c += cstats[j * NB + b];
#pragma unroll
    for (int o = 1; o < 32; o <<= 1) c += __shfl_xor(c, o, 64);
    if (ln == 0) red[t] = (float)c * (1.0f / 128.0f);
    __syncthreads();
    if (tid == 0) {
      float a = 0.f;
      for (int tt = 0; tt < TSTEPS; ++tt) a = __fadd_rn(a, red[tt]);
      d_out[40965 + i] = a / 4096.0f;
    }
  }
}

// ---------- launch ----------
extern "C" void kernel_launch(void* const* d_in, const int* in_sizes, int n_in,
                              void* d_out, int out_size, void* d_ws, size_t ws_size,
                              hipStream_t stream) {
  const float* input = (const float*)d_in[0];
  const float* W0 = (const float*)d_in[1];
  const float* W1 = (const float*)d_in[2];
  const float* W2 = (const float*)d_in[3];
  const float* W3 = (const float*)d_in[4];
  const float* W4 = (const float*)d_in[5];
  const float* b0 = (const float*)d_in[6];
  const float* b1 = (const float*)d_in[7];
  const float* b2 = (const float*)d_in[8];
  const float* b3 = (const float*)d_in[9];
  const float* b4 = (const float*)d_in[10];

  uint8_t* ws = (uint8_t*)d_ws;
  signed char* ws0  = (signed char*)(ws + OFF_WS0);
  signed char* ws1  = (signed char*)(ws + OFF_WS1);
  signed char* ws2  = (signed char*)(ws + OFF_WS2);
  signed char* ws3  = (signed char*)(ws + OFF_WS3);
  float* w4t        = (float*)(ws + OFF_W4T);
  signed char* spkA = (signed char*)(ws + OFF_SPKA);
  signed char* spkB = (signed char*)(ws + OFF_SPKB);
  float* cur        = (float*)(ws + OFF_CUR);
  float* cur5p      = (float*)(ws + OFF_CUR5P);
  float* vst        = (float*)(ws + OFF_VST);
  int* cst          = (int*)(ws + OFF_CST);
  float* out        = (float*)d_out;

  hipMemsetAsync(ws + OFF_VST, 0, SZ_VST + SZ_CST + SZ_CUR5P, stream);
  hipMemsetAsync(ws + OFF_SPKA, 0, (size_t)TSTEPS * BATCH * KA0, stream);
  hipMemsetAsync(ws + OFF_WS0, 0, SZ_WS0, stream);

  k_wsplit_all<<<1568 + 3 * 4096, 256, 0, stream>>>(W0, W1, W2, W3, ws0, ws1, ws2, ws3);
  k_w4t<<<8, 256, 0, stream>>>(W4, w4t);

  k_scan0<<<BATCH, 128, 0, stream>>>(input, spkA, vst, cst);
  k_gemm3p<<<512, 256, 0, stream>>>(spkA, ws0, cur, 2048, KA0);
  k_scan<<<512, 128, 0, stream>>>(cur, b0, spkB, vst, cst, 1);
  k_gemm3p<<<512, 256, 0, stream>>>(spkB, ws1, cur, 2048, 2048);
  k_scan<<<512, 128, 0, stream>>>(cur, b1, spkA, vst, cst, 2);
  k_gemm3p<<<512, 256, 0, stream>>>(spkA, ws2, cur, 2048, 2048);
  k_scan<<<512, 128, 0, stream>>>(cur, b2, spkB, vst, cst, 3);
  k_gemm3p<<<512, 256, 0, stream>>>(spkB, ws3, cur, 2048, 2048);
  k_scan<<<512, 128, 0, stream>>>(cur, b3, spkA, vst, cst, 4);
  k_gemm4<<<2048, 256, 0, stream>>>(spkA, w4t, cur5p);
  k_scan5<<<2, 640, 0, stream>>>(cur5p, b4, out + 5, cst);
  k_final<<<11, 1024, 0, stream>>>(vst, cst, out);
}